// Round 13
// baseline (312.248 us; speedup 1.0000x reference)
//
#include <hip/hip_runtime.h>
#include <stdint.h>

typedef unsigned short u16;
typedef __attribute__((ext_vector_type(8))) short short8;
typedef __attribute__((ext_vector_type(16))) float f32x16;

#define M_DIM 8192
#define N_DIM 4096
#define K_DIM 4096

// ---------- fp32 -> bf16 (RNE), 8 elems/thread ----------
__device__ inline u16 f32_to_bf16_rne(float f) {
    uint32_t b = __builtin_bit_cast(uint32_t, f);
    b += 0x7fffu + ((b >> 16) & 1u);
    return (u16)(b >> 16);
}

__global__ __launch_bounds__(256)
void cvt_f32_to_bf16_k(const float* __restrict__ in, u16* __restrict__ out, int n_vec8) {
    int stride = gridDim.x * blockDim.x;
    for (int i = blockIdx.x * blockDim.x + threadIdx.x; i < n_vec8; i += stride) {
        const float4* p = reinterpret_cast<const float4*>(in) + 2 * (size_t)i;
        float4 a = p[0];
        float4 b = p[1];
        float v[8] = {a.x, a.y, a.z, a.w, b.x, b.y, b.z, b.w};
        short8 r;
#pragma unroll
        for (int j = 0; j < 8; ++j) r[j] = (short)f32_to_bf16_rne(v[j]);
        *reinterpret_cast<short8*>(out + 8 * (size_t)i) = r;
    }
}

// ---------- 256x256 bf16 GEMM on mfma_f32_32x32x16_bf16 ----------
// A: [M][K] bf16, B: [N][K] bf16 (B^T), C: [M][N] f32
// 512 threads = 8 waves (2M x 4N); per-wave 128x64 = 4 m-tiles x 2 n-tiles of 32^2.
// LDS: [dbuf][mat][half][128*64] bf16 = 128 KiB. Swizzle S(a)=a^(((a>>7)&7)<<4).
// Frag layout (32x32x16): A/B row=lane&31, k=(lane>>5)*8+j (8 bf16 = 1 b128);
// C/D col=lane&31, row=(reg&3)+8*(reg>>2)+4*(lane>>5) [m74/m101-verified].
// Swizzle folds into 16 per-(buf,mat,ks) base pointers: XOR-range term
// ks*32+(lane>>5)*16 < 128 (no carry past bit 6); mt/nt*4096 added after.
//
// 8 phases/iter = 8 k-slices: quads a.ks0..3 (P1-4), b.ks0..3 (P5-8).
// Reads JIT one phase ahead, UNIFORM 6 ds_read/phase -> LGKM(6) every phase
// (outstanding 12, drains exactly prev phase's 6). Read issue at P_p feeds
// quad P_{p+1}: P1->a.ks1 ... P7->b.ks3, P8->(a+2).ks0; prologue issues a.ks0.
// Stages: P1 = all 4 halves of tile b (buf1, 8 DMA); P5 = all 4 of (a+2)
// (buf0). VM0 at P3-close (publish b; youngest DMA 2 phases old ~1100cyc >
// 900 HBM) and P7-close (publish a+2). Stage WAR: buf1 prior reads drained
// prev-P8 LGKM -> stage P1 OK; buf0 drained P4 LGKM -> stage P5 OK; P8 reads
// buf0's NEW tile published P7-close. Reg sets alternate by phase parity;
// every overwrite >=1 phase after last MFMA use.

#define BAR() do { asm volatile("" ::: "memory"); __builtin_amdgcn_s_barrier(); asm volatile("" ::: "memory"); } while (0)
#define LGKM(n) do { asm volatile("s_waitcnt lgkmcnt(" #n ")" ::: "memory"); __builtin_amdgcn_sched_barrier(0); } while (0)
#define WAIT_VM0() asm volatile("s_waitcnt vmcnt(0)" ::: "memory")

// 8 MFMA: 4 m-tiles x 2 n-tiles at one k-slice
#define QUAD8(AA, BB)                                                             \
    _Pragma("unroll")                                                             \
    for (int mt = 0; mt < 4; ++mt) {                                              \
        _Pragma("unroll")                                                         \
        for (int nt = 0; nt < 2; ++nt) {                                          \
            acc[mt][nt] = __builtin_amdgcn_mfma_f32_32x32x16_bf16(                \
                AA[mt], BB[nt], acc[mt][nt], 0, 0, 0);                            \
        }                                                                         \
    }

#define READ_A4(AA, P)                                                            \
    _Pragma("unroll")                                                             \
    for (int mt = 0; mt < 4; ++mt) {                                              \
        AA[mt] = *reinterpret_cast<const short8*>((P) + mt * 4096);               \
    }

#define READ_B2(BB, P)                                                            \
    _Pragma("unroll")                                                             \
    for (int nt = 0; nt < 2; ++nt) {                                              \
        BB[nt] = *reinterpret_cast<const short8*>((P) + nt * 4096);               \
    }

__global__ __launch_bounds__(512, 2)
void gemm_8phase(const u16* __restrict__ A, const u16* __restrict__ B,
                 const float* __restrict__ bias, float* __restrict__ C) {
    __shared__ __align__(16) u16 lds[2][2][2][128 * 64];   // 128 KiB

    const int tid  = threadIdx.x;
    const int wave = tid >> 6;
    const int lane = tid & 63;

    // T1: XCD-aware bijective swizzle (nwg=512, 512%8==0)
    const uint32_t wg = (blockIdx.x & 7u) * 64u + (blockIdx.x >> 3);
    const int bx = (int)(wg % (N_DIM / 256));
    const int by = (int)(wg / (N_DIM / 256));
    const int brow = by * 256;
    const int bcol = bx * 256;

    const int wr = wave >> 2;   // 0..1 -> 128 output rows each
    const int wc = wave & 3;    // 0..3 -> 64 output cols each

    // staging: physical chunk cp (linear gload_lds dest) holds LOGICAL chunk
    // cl = cp ^ ((cp>>3)&7)  (16B-chunk form of S; involution)
    const uint32_t cp0 = (uint32_t)(wave * 64 + lane);
    const uint32_t cp1 = cp0 + 512u;
    const uint32_t cl0 = cp0 ^ ((cp0 >> 3) & 7u);
    const uint32_t cl1 = cp1 ^ ((cp1 >> 3) & 7u);
    const uint32_t sr0 = cl0 >> 3, sc0 = (cl0 & 7u) * 8u;
    const uint32_t sr1 = cl1 >> 3, sc1 = (cl1 & 7u) * 8u;

    const u16* pA[2] = { A + (size_t)(brow)       * K_DIM,
                         A + (size_t)(brow + 128) * K_DIM };
    const u16* pB[2] = { B + (size_t)(bcol)       * K_DIM,
                         B + (size_t)(bcol + 128) * K_DIM };

    // per-lane swizzled ds_read bases for each (buf, mat, ks)
    const uint32_t sw = (uint32_t)(lane & 7) << 4;
    const uint32_t lrow = (uint32_t)(lane & 31) * 128u;
    const uint32_t khi  = (uint32_t)(lane >> 5) * 16u;

    const char* As0 = (const char*)&lds[0][0][wr][0];
    const char* As1 = (const char*)&lds[1][0][wr][0];
    const char* Bs0 = (const char*)&lds[0][1][wc >> 1][0] + (uint32_t)(wc & 1) * 8192u;
    const char* Bs1 = (const char*)&lds[1][1][wc >> 1][0] + (uint32_t)(wc & 1) * 8192u;

    const char* pA0[4]; const char* pA1[4]; const char* pB0[4]; const char* pB1[4];
#pragma unroll
    for (int ks = 0; ks < 4; ++ks) {
        const uint32_t off = (lrow + (uint32_t)ks * 32u + khi) ^ sw;
        pA0[ks] = As0 + off;
        pA1[ks] = As1 + off;
        pB0[ks] = Bs0 + off;
        pB1[ks] = Bs1 + off;
    }

    auto STAGE = [&](const u16* gbase, u16* lhalf, int k0) {
        __builtin_amdgcn_global_load_lds(
            (const __attribute__((address_space(1))) uint32_t*)(gbase + (size_t)sr0 * K_DIM + k0 + sc0),
            (__attribute__((address_space(3))) uint32_t*)(lhalf + wave * 512), 16, 0, 0);
        __builtin_amdgcn_global_load_lds(
            (const __attribute__((address_space(1))) uint32_t*)(gbase + (size_t)sr1 * K_DIM + k0 + sc1),
            (__attribute__((address_space(3))) uint32_t*)(lhalf + 4096 + wave * 512), 16, 0, 0);
    };

    f32x16 acc[4][2];
#pragma unroll
    for (int mt = 0; mt < 4; ++mt)
#pragma unroll
        for (int nt = 0; nt < 2; ++nt)
#pragma unroll
            for (int j = 0; j < 16; ++j) acc[mt][nt][j] = 0.f;

    short8 a0[4], a1[4], b0[2], b1[2];   // set0 = {a0,b0}, set1 = {a1,b1}

    // ---- prologue: tile a=0 (4 halves); VM0; pre-issue set0 <- a.ks0 ----
    STAGE(pA[0], &lds[0][0][0][0], 0);
    STAGE(pA[1], &lds[0][0][1][0], 0);
    STAGE(pB[0], &lds[0][1][0][0], 0);
    STAGE(pB[1], &lds[0][1][1][0], 0);
    WAIT_VM0();
    BAR();
    READ_A4(a0, pA0[0]);
    READ_B2(b0, pB0[0]);

    // ---- main loop: iter i computes tiles a=2i (buf0), b=2i+1 (buf1) ----
    for (int i = 0; i < K_DIM / 128; ++i) {
        const int k_b  = (2 * i + 1) * 64;                   // <= 4032
        const int k_a2 = ((2 * i + 2) * 64) & (K_DIM - 1);   // wraps harmlessly last iter

        // P1: rd set1 <- a.ks1 | stage tile b (4 halves) | Q(set0: a.ks0)
        READ_A4(a1, pA0[1]);
        READ_B2(b1, pB0[1]);
        STAGE(pA[0], &lds[1][0][0][0], k_b);
        STAGE(pA[1], &lds[1][0][1][0], k_b);
        STAGE(pB[0], &lds[1][1][0][0], k_b);
        STAGE(pB[1], &lds[1][1][1][0], k_b);
        BAR(); LGKM(6);
        __builtin_amdgcn_s_setprio(1);
        QUAD8(a0, b0);
        __builtin_amdgcn_s_setprio(0);
        BAR();

        // P2: rd set0 <- a.ks2 | Q(set1: a.ks1)
        READ_A4(a0, pA0[2]);
        READ_B2(b0, pB0[2]);
        BAR(); LGKM(6);
        __builtin_amdgcn_s_setprio(1);
        QUAD8(a1, b1);
        __builtin_amdgcn_s_setprio(0);
        BAR();

        // P3: rd set1 <- a.ks3 | Q(set0: a.ks2) | VM0: publish tile b
        READ_A4(a1, pA0[3]);
        READ_B2(b1, pB0[3]);
        BAR(); LGKM(6);
        __builtin_amdgcn_s_setprio(1);
        QUAD8(a0, b0);
        __builtin_amdgcn_s_setprio(0);
        WAIT_VM0();
        BAR();

        // P4: rd set0 <- b.ks0 | Q(set1: a.ks3)
        READ_A4(a0, pA1[0]);
        READ_B2(b0, pB1[0]);
        BAR(); LGKM(6);
        __builtin_amdgcn_s_setprio(1);
        QUAD8(a1, b1);
        __builtin_amdgcn_s_setprio(0);
        BAR();

        // P5: rd set1 <- b.ks1 | stage tile a+2 (4 halves) | Q(set0: b.ks0)
        READ_A4(a1, pA1[1]);
        READ_B2(b1, pB1[1]);
        STAGE(pA[0], &lds[0][0][0][0], k_a2);
        STAGE(pA[1], &lds[0][0][1][0], k_a2);
        STAGE(pB[0], &lds[0][1][0][0], k_a2);
        STAGE(pB[1], &lds[0][1][1][0], k_a2);
        BAR(); LGKM(6);
        __builtin_amdgcn_s_setprio(1);
        QUAD8(a0, b0);
        __builtin_amdgcn_s_setprio(0);
        BAR();

        // P6: rd set0 <- b.ks2 | Q(set1: b.ks1)
        READ_A4(a0, pA1[2]);
        READ_B2(b0, pB1[2]);
        BAR(); LGKM(6);
        __builtin_amdgcn_s_setprio(1);
        QUAD8(a1, b1);
        __builtin_amdgcn_s_setprio(0);
        BAR();

        // P7: rd set1 <- b.ks3 | Q(set0: b.ks2) | VM0: publish a+2
        READ_A4(a1, pA1[3]);
        READ_B2(b1, pB1[3]);
        BAR(); LGKM(6);
        __builtin_amdgcn_s_setprio(1);
        QUAD8(a0, b0);
        __builtin_amdgcn_s_setprio(0);
        WAIT_VM0();
        BAR();

        // P8: rd set0 <- (a+2).ks0 | Q(set1: b.ks3)
        READ_A4(a0, pA0[0]);
        READ_B2(b0, pB0[0]);
        BAR(); LGKM(6);
        __builtin_amdgcn_s_setprio(1);
        QUAD8(a1, b1);
        __builtin_amdgcn_s_setprio(0);
        BAR();
    }

    WAIT_VM0();    // drain wrapped prefetches
    LGKM(0);       // drain dangling P8 reads before epilogue reuses regs

    // ---- epilogue: 32x32 C/D layout col=lane&31, row=(r&3)+8*(r>>2)+4*(lane>>5) ----
    const int orow = brow + wr * 128 + 4 * (lane >> 5);
    const int ocol = bcol + wc * 64 + (lane & 31);
#pragma unroll
    for (int mt = 0; mt < 4; ++mt) {
#pragma unroll
        for (int nt = 0; nt < 2; ++nt) {
            const int c = ocol + nt * 32;
            const float bv = bias[c];
#pragma unroll
            for (int r = 0; r < 16; ++r) {
                const int row = orow + mt * 32 + (r & 3) + 8 * (r >> 2);
                C[(size_t)row * N_DIM + c] = acc[mt][nt][r] + bv;
            }
        }
    }
}

// ---------- fallback (ws too small): correct, slow fp32 ----------
__global__ __launch_bounds__(256)
void gemm_f32_naive(const float* __restrict__ x, const float* __restrict__ w,
                    const float* __restrict__ bias, float* __restrict__ out) {
    const size_t total = (size_t)M_DIM * N_DIM;
    const size_t stride = (size_t)gridDim.x * blockDim.x;
    for (size_t idx = (size_t)blockIdx.x * blockDim.x + threadIdx.x; idx < total; idx += stride) {
        const int b = (int)(idx / N_DIM);
        const int o = (int)(idx % N_DIM);
        const float* xr = x + (size_t)b * K_DIM;
        const float* wr = w + (size_t)o * K_DIM;
        float s = bias[o];
        for (int k = 0; k < K_DIM; ++k) s = fmaf(xr[k], wr[k], s);
        out[idx] = s;
    }
}

extern "C" void kernel_launch(void* const* d_in, const int* in_sizes, int n_in,
                              void* d_out, int out_size, void* d_ws, size_t ws_size,
                              hipStream_t stream) {
    const float* x    = (const float*)d_in[0];
    const float* w    = (const float*)d_in[1];
    const float* bias = (const float*)d_in[2];
    float* out = (float*)d_out;

    const size_t xb_elems = (size_t)M_DIM * K_DIM;
    const size_t wb_elems = (size_t)N_DIM * K_DIM;
    const size_t need = (xb_elems + wb_elems) * sizeof(u16);

    if (ws_size >= need) {
        u16* xb = (u16*)d_ws;
        u16* wb = xb + xb_elems;
        cvt_f32_to_bf16_k<<<2048, 256, 0, stream>>>(x, xb, (int)(xb_elems / 8));
        cvt_f32_to_bf16_k<<<2048, 256, 0, stream>>>(w, wb, (int)(wb_elems / 8));
        const int nwg = (M_DIM / 256) * (N_DIM / 256);   // 32*16 = 512
        gemm_8phase<<<nwg, 512, 0, stream>>>(xb, wb, bias, out);
    } else {
        gemm_f32_naive<<<4096, 256, 0, stream>>>(x, w, bias, out);
    }
}